// Round 10
// baseline (122.454 us; speedup 1.0000x reference)
//
#include <hip/hip_runtime.h>

#define SRC_LEN 256
#define TRG_LEN 256
#define BATCH   32
#define HID     512
#define ATT     128
#define CSCALE  2.885390081777927f   // 2*log2(e): exp2(CSCALE*x) == exp(2x)

typedef float  f32x4  __attribute__((ext_vector_type(4)));
typedef short  bf16x8 __attribute__((ext_vector_type(8)));

// manual RNE fp32->bf16 (inputs are finite normals; NaN path not needed)
__device__ inline unsigned short bfr(float x) {
    unsigned u = __builtin_bit_cast(unsigned, x);
    return (unsigned short)((u + 0x7fffu + ((u >> 16) & 1u)) >> 16);
}
__device__ inline unsigned pk2(float a, float b) {
    return (unsigned)bfr(a) | ((unsigned)bfr(b) << 16);
}

// ---------------------------------------------------------------------------
// MFMA projection v6: 1024 blocks x 256 threads, 16-row x 128-a tiles.
// R9 ledger: proj_v5 (1 block/CU) ~22 us vs ~3 us pipe work -> barrier-
// coupled latency. v6 gets 4 independent blocks/CU (36 KB LDS x 4 = 144 KB,
// 16 waves/CU = 4/SIMD in 4 decoupled barrier domains) while KEEPING all
// staging coalesced + W in LDS (R5 lesson: divergent W loads cost +14.5 us).
// W L2 traffic doubles to ~256 MB (~7.4 us aggregate, L2-resident - W is
// only 512 KB). Same dbuf, same XOR swizzle, 1 barrier/chunk.
// Wave w: n-cols w*32 (2 mfma tiles), m = all 16 rows.
// ---------------------------------------------------------------------------
__global__ __launch_bounds__(256, 4) void proj_mfma(
    const float* __restrict__ dec_out, const float* __restrict__ enc_outs,
    const float* __restrict__ W_s, const float* __restrict__ W_t,
    const float* __restrict__ b_t,
    float* __restrict__ encE, float* __restrict__ decD)
{
    __shared__ __align__(16) char smem[36864];
    char* aLb = smem;            // [2][16 rows][128 B] = 4 KB
    char* bLb = smem + 4096;     // [2][128 rows][128 B] = 32 KB

    const int tid   = threadIdx.x;
    const int blk   = blockIdx.x;
    const bool isDec = blk >= 512;
    const int idx   = blk & 511;
    const int bb    = idx & 31;
    const int r0    = (idx >> 5) * 16;             // s0 or t0
    const float* __restrict__ in = isDec ? dec_out : enc_outs;
    const float* __restrict__ W  = isDec ? W_t : W_s;

    const int lane = tid & 63;
    const int w    = tid >> 6;        // 0..3: n-cols w*32 .. w*32+31
    const int q    = lane >> 4;
    const int l15  = lane & 15;
    const int l7   = lane & 7;

    // staging mapping: A row = tid>>4 (0..15), W rows = (tid>>4)+it*16;
    // float4 col = tid&15. Consecutive tids -> consecutive 16B: coalesced.
    const int srow = tid >> 4;
    const int skc  = tid & 15;
    const int sg   = skc >> 1, shalf = skc & 1;   // 16B LDS group, 8B half
    const float* aGp = in + ((size_t)(r0 + srow) * BATCH + bb) * HID + skc * 4;
    const float* wGp = W + (size_t)srow * HID + skc * 4;

    float4 aR;      // A row srow
    float4 wR[8];   // W rows srow + it*16

    f32x4 acc[2];
    acc[0] = (f32x4)0.0f;
    acc[1] = (f32x4)0.0f;

    #define LOADG(c)                                                          \
        {                                                                     \
            aR = *(const float4*)(aGp + (c) * 64);                            \
            _Pragma("unroll")                                                 \
            for (int it = 0; it < 8; ++it)                                    \
                wR[it] = *(const float4*)(wGp + (size_t)it * 16 * HID         \
                                          + (c) * 64);                        \
        }

    #define STORES(buf)                                                      \
        {                                                                    \
            char* ab = aLb + (buf) * 2048;                                   \
            {                                                                \
                uint2 u;                                                     \
                u.x = pk2(aR.x, aR.y);                                       \
                u.y = pk2(aR.z, aR.w);                                       \
                *(uint2*)(ab + srow * 128 + ((sg ^ (srow & 7)) << 4)         \
                          + shalf * 8) = u;                                  \
            }                                                                \
            char* bp = bLb + (buf) * 16384;                                  \
            _Pragma("unroll")                                                \
            for (int it = 0; it < 8; ++it) {                                 \
                const int rw = srow + it * 16;                               \
                uint2 u;                                                     \
                u.x = pk2(wR[it].x, wR[it].y);                               \
                u.y = pk2(wR[it].z, wR[it].w);                               \
                *(uint2*)(bp + rw * 128 + ((sg ^ (rw & 7)) << 4)             \
                          + shalf * 8) = u;                                  \
            }                                                                \
        }

    LOADG(0);
    STORES(0);
    __syncthreads();

    for (int c = 0; c < 8; ++c) {
        if (c < 7) LOADG(c + 1);
        const char* ab = aLb + (c & 1) * 2048;
        const char* bp = bLb + (c & 1) * 16384;
        #pragma unroll
        for (int s = 0; s < 2; ++s) {
            const int sw = ((s * 4 + q) ^ l7) * 16;
            bf16x8 af = *(const bf16x8*)(ab + l15 * 128 + sw);
            bf16x8 b0 = *(const bf16x8*)(bp + (w * 32 + l15) * 128 + sw);
            bf16x8 b1 = *(const bf16x8*)(bp + (w * 32 + 16 + l15) * 128 + sw);
            acc[0] = __builtin_amdgcn_mfma_f32_16x16x32_bf16(af, b0, acc[0], 0, 0, 0);
            acc[1] = __builtin_amdgcn_mfma_f32_16x16x32_bf16(af, b1, acc[1], 0, 0, 0);
        }
        if (c < 7) STORES((c + 1) & 1);
        __syncthreads();
    }

    if (!isDec) {
        // E' = exp(-2*enc_att) -> LDS transpose (16 x 128, stride 132) ->
        // [b][a>>2][s][4] store: one coalesced float4 per lane for score.
        float* T = (float*)smem;
        #pragma unroll
        for (int ni = 0; ni < 2; ++ni)
            #pragma unroll
            for (int r = 0; r < 4; ++r) {
                const int ml = q * 4 + r;                 // s-local 0..15
                const int nl = w * 32 + ni * 16 + l15;    // a 0..127
                T[ml * 132 + nl] = __builtin_amdgcn_exp2f(-CSCALE * acc[ni][r]);
            }
        __syncthreads();
        {
            const int m  = tid & 15;     // s-local
            const int g0 = tid >> 4;     // 0..15
            #pragma unroll
            for (int p = 0; p < 2; ++p) {
                const int gq = g0 + p * 16;          // a-quad 0..31
                float4 v = *(const float4*)(T + m * 132 + gq * 4);
                *(float4*)(encE + (((size_t)bb * 32 + gq) * SRC_LEN + r0 + m) * 4) = v;
            }
        }
    } else {
        // D = exp(+2*(dec_att + b_t)), natural [t][b][a] store
        float bt0 = b_t[w * 32 + l15];
        float bt1 = b_t[w * 32 + 16 + l15];
        #pragma unroll
        for (int r = 0; r < 4; ++r) {
            const int t = r0 + q * 4 + r;
            decD[((size_t)t * BATCH + bb) * ATT + w * 32 + l15] =
                __builtin_amdgcn_exp2f(CSCALE * (acc[0][r] + bt0));
            decD[((size_t)t * BATCH + bb) * ATT + w * 32 + 16 + l15] =
                __builtin_amdgcn_exp2f(CSCALE * (acc[1][r] + bt1));
        }
    }
    #undef LOADG
    #undef STORES
}

// ---------------------------------------------------------------------------
// Score v6 (unchanged, ~36.5 us measured): 4-term rational, 1 rcp per 4
// elements; encE in [b][gq][s][4] -> one dwordx4 per g; full unroll,
// no branches; D,v via LDS broadcast (R6 A/B: beats uniform global).
// ---------------------------------------------------------------------------
__global__ __launch_bounds__(256) void score_kernel(
    const float* __restrict__ encE, const float* __restrict__ decD,
    const float* __restrict__ v_a, float* __restrict__ out)
{
    __shared__ float dS[4 * ATT];
    __shared__ float vS[ATT];
    __shared__ float sumvS;

    const int tid = threadIdx.x;
    const int t0  = blockIdx.x * 4;
    const int b   = blockIdx.y;

    if (tid < 128) {
        const int tt = tid >> 5, a4 = (tid & 31) * 4;
        *(float4*)(dS + tt * ATT + a4) =
            *(const float4*)(decD + ((size_t)(t0 + tt) * BATCH + b) * ATT + a4);
    } else if (tid < 160) {
        const int l = tid - 128;
        *(float4*)(vS + l * 4) = *(const float4*)(v_a + l * 4);
    }
    __syncthreads();
    if (tid < 64) {
        float x = vS[tid] + vS[tid + 64];
        #pragma unroll
        for (int o = 32; o > 0; o >>= 1) x += __shfl_down(x, o);
        if (tid == 0) sumvS = x;
    }
    __syncthreads();

    float acc0 = 0.f, acc1 = 0.f, acc2 = 0.f, acc3 = 0.f;
    const float* __restrict__ ep = encE + ((size_t)b * 32 * SRC_LEN + tid) * 4;

    #pragma unroll
    for (int g = 0; g < 32; ++g) {
        const float4 E  = *(const float4*)(ep + (size_t)g * SRC_LEN * 4);
        const float4 vv = *(const float4*)(vS + g * 4);
        const float n0 = vv.x * E.x, n1 = vv.y * E.y;
        const float n2 = vv.z * E.z, n3 = vv.w * E.w;

        #define TSTEP(ACC, DBASE)                                          \
        {                                                                  \
            const float4 d = *(const float4*)(DBASE + g * 4);              \
            const float x0 = E.x + d.x, x1 = E.y + d.y;                    \
            const float x2 = E.z + d.z, x3 = E.w + d.w;                    \
            const float a01 = x0 * x1, a23 = x2 * x3;                      \
            const float den = a01 * a23;                                   \
            const float m01 = fmaf(n0, x1, n1 * x0);                       \
            const float m23 = fmaf(n2, x3, n3 * x2);                       \
            const float num = fmaf(m01, a23, m23 * a01);                   \
            ACC = fmaf(num, __builtin_amdgcn_rcpf(den), ACC);              \
        }
        TSTEP(acc0, dS + 0 * ATT)
        TSTEP(acc1, dS + 1 * ATT)
        TSTEP(acc2, dS + 2 * ATT)
        TSTEP(acc3, dS + 3 * ATT)
        #undef TSTEP
    }

    const float sv = sumvS;
    out[((size_t)(t0 + 0) * BATCH + b) * SRC_LEN + tid] = sv - 2.0f * acc0;
    out[((size_t)(t0 + 1) * BATCH + b) * SRC_LEN + tid] = sv - 2.0f * acc1;
    out[((size_t)(t0 + 2) * BATCH + b) * SRC_LEN + tid] = sv - 2.0f * acc2;
    out[((size_t)(t0 + 3) * BATCH + b) * SRC_LEN + tid] = sv - 2.0f * acc3;
}

extern "C" void kernel_launch(void* const* d_in, const int* in_sizes, int n_in,
                              void* d_out, int out_size, void* d_ws, size_t ws_size,
                              hipStream_t stream) {
    const float* dec_out  = (const float*)d_in[0];
    const float* enc_outs = (const float*)d_in[1];
    const float* W_s      = (const float*)d_in[2];
    const float* W_t      = (const float*)d_in[3];
    const float* b_t      = (const float*)d_in[4];
    const float* v_a      = (const float*)d_in[5];
    float* out = (float*)d_out;

    float* encE = (float*)d_ws;                              // B*32*S*4 = 4 MB : exp(-2*enc_att), [b][a>>2][s][4]
    float* decD = encE + (size_t)BATCH * ATT * SRC_LEN;      // T*B*A    = 4 MB : exp(+2*dec_att), [t][b][a]

    proj_mfma<<<1024, 256, 0, stream>>>(dec_out, enc_outs, W_s, W_t, b_t, encE, decD);

    dim3 g3(TRG_LEN / 4, BATCH);
    score_kernel<<<g3, 256, 0, stream>>>(encE, decD, v_a, out);
}

// Round 11
// 116.781 us; speedup vs baseline: 1.0486x; 1.0486x over previous
//
#include <hip/hip_runtime.h>

#define SRC_LEN 256
#define TRG_LEN 256
#define BATCH   32
#define HID     512
#define ATT     128
#define CSCALE  2.885390081777927f   // 2*log2(e): exp2(CSCALE*x) == exp(2x)

typedef float  f32x4  __attribute__((ext_vector_type(4)));
typedef float  f32x2  __attribute__((ext_vector_type(2)));
typedef short  bf16x8 __attribute__((ext_vector_type(8)));

// manual RNE fp32->bf16 (inputs are finite normals; NaN path not needed)
__device__ inline unsigned short bfr(float x) {
    unsigned u = __builtin_bit_cast(unsigned, x);
    return (unsigned short)((u + 0x7fffu + ((u >> 16) & 1u)) >> 16);
}
__device__ inline unsigned pk2(float a, float b) {
    return (unsigned)bfr(a) | ((unsigned)bfr(b) << 16);
}

// ---------------------------------------------------------------------------
// MFMA projection v5 — EXACT revert to the R9-measured-best version (~22 us):
// 256 blocks x 512 threads, 64-row x 128-a tile, coalesced dbuf LDS staging.
// R10 lesson: 16-row tiles (4 blocks/CU) quadruple W-staging redundancy and
// regress +6.6 us — staging:compute ratio dominates over barrier decoupling.
// R5 lesson: divergent per-k W loads cost +14.5 us. Tile shape is settled.
// ---------------------------------------------------------------------------
__global__ __launch_bounds__(512) void proj_mfma(
    const float* __restrict__ dec_out, const float* __restrict__ enc_outs,
    const float* __restrict__ W_s, const float* __restrict__ W_t,
    const float* __restrict__ b_t,
    float* __restrict__ encE, float* __restrict__ decD)
{
    __shared__ __align__(16) char smem[49152];
    char* aLb = smem;            // [2][64 rows][128 B] = 16 KB
    char* bLb = smem + 16384;    // [2][128 rows][128 B] = 32 KB

    const int tid   = threadIdx.x;
    const int blk   = blockIdx.x;
    const bool isDec = blk >= 128;
    const int bb    = blk & 31;
    const int r0    = ((isDec ? blk - 128 : blk) >> 5) * 64;  // s0 or t0
    const float* __restrict__ in = isDec ? dec_out : enc_outs;
    const float* __restrict__ W  = isDec ? W_t : W_s;

    const int lane   = tid & 63;
    const int w      = tid >> 6;        // 0..7
    const int woff_m = (w & 3) * 16;
    const int woff_n = (w >> 2) * 64;
    const int q      = lane >> 4;
    const int l15    = lane & 15;
    const int l7     = lane & 7;

    const int srow = tid >> 4;
    const int skc  = tid & 15;
    const int sg   = skc >> 1, shalf = skc & 1;   // 16B LDS group, 8B half
    const float* aGp = in + ((size_t)(r0 + srow) * BATCH + bb) * HID + skc * 4;
    const float* wGp = W + (size_t)srow * HID + skc * 4;

    float4 aR[2];   // A rows srow, srow+32
    float4 wR[4];   // W rows srow + it*32

    f32x4 acc[4];
    #pragma unroll
    for (int ni = 0; ni < 4; ++ni) acc[ni] = (f32x4)0.0f;

    #define LOADG(c)                                                          \
        {                                                                     \
            _Pragma("unroll")                                                 \
            for (int it = 0; it < 2; ++it)                                    \
                aR[it] = *(const float4*)(aGp + (size_t)it * 32 * BATCH * HID \
                                          + (c) * 64);                        \
            _Pragma("unroll")                                                 \
            for (int it = 0; it < 4; ++it)                                    \
                wR[it] = *(const float4*)(wGp + (size_t)it * 32 * HID         \
                                          + (c) * 64);                        \
        }

    #define STORES(buf)                                                      \
        {                                                                    \
            char* ab = aLb + (buf) * 8192;                                   \
            _Pragma("unroll")                                                \
            for (int it = 0; it < 2; ++it) {                                 \
                const int i = srow + it * 32;                                \
                uint2 u;                                                     \
                u.x = pk2(aR[it].x, aR[it].y);                               \
                u.y = pk2(aR[it].z, aR[it].w);                               \
                *(uint2*)(ab + i * 128 + ((sg ^ (i & 7)) << 4)               \
                          + shalf * 8) = u;                                  \
            }                                                                \
            char* bp = bLb + (buf) * 16384;                                  \
            _Pragma("unroll")                                                \
            for (int it = 0; it < 4; ++it) {                                 \
                const int rw = srow + it * 32;                               \
                uint2 u;                                                     \
                u.x = pk2(wR[it].x, wR[it].y);                               \
                u.y = pk2(wR[it].z, wR[it].w);                               \
                *(uint2*)(bp + rw * 128 + ((sg ^ (rw & 7)) << 4)             \
                          + shalf * 8) = u;                                  \
            }                                                                \
        }

    LOADG(0);
    STORES(0);
    __syncthreads();

    for (int c = 0; c < 8; ++c) {
        if (c < 7) LOADG(c + 1);
        const char* ab = aLb + (c & 1) * 8192;
        const char* bp = bLb + (c & 1) * 16384;
        #pragma unroll
        for (int s = 0; s < 2; ++s) {
            const int sw = ((s * 4 + q) ^ l7) * 16;
            bf16x8 af = *(const bf16x8*)(ab + (woff_m + l15) * 128 + sw);
            bf16x8 bfv[4];
            #pragma unroll
            for (int ni = 0; ni < 4; ++ni)
                bfv[ni] = *(const bf16x8*)(bp + (woff_n + ni * 16 + l15) * 128 + sw);
            #pragma unroll
            for (int ni = 0; ni < 4; ++ni)
                acc[ni] = __builtin_amdgcn_mfma_f32_16x16x32_bf16(
                    af, bfv[ni], acc[ni], 0, 0, 0);
        }
        if (c < 7) STORES((c + 1) & 1);
        __syncthreads();
    }

    if (!isDec) {
        // E' = exp(-2*enc_att) -> LDS transpose (stride 132, float4-aligned)
        // -> [b][a>>2][s][4] store: one coalesced float4 per lane for score.
        float* T = (float*)smem;
        #pragma unroll
        for (int ni = 0; ni < 4; ++ni)
            #pragma unroll
            for (int r = 0; r < 4; ++r) {
                const int ml = woff_m + q * 4 + r;
                const int nl = woff_n + ni * 16 + l15;
                T[ml * 132 + nl] = __builtin_amdgcn_exp2f(-CSCALE * acc[ni][r]);
            }
        __syncthreads();
        {
            const int m  = tid & 63;     // s-local
            const int g0 = tid >> 6;     // 0..7
            #pragma unroll
            for (int p = 0; p < 4; ++p) {
                const int gq = g0 + p * 8;          // a-quad 0..31
                float4 v = *(const float4*)(T + m * 132 + gq * 4);
                *(float4*)(encE + (((size_t)bb * 32 + gq) * SRC_LEN + r0 + m) * 4) = v;
            }
        }
    } else {
        // D = exp(+2*(dec_att + b_t)), natural [t][b][a] store
        float bt[4];
        #pragma unroll
        for (int ni = 0; ni < 4; ++ni) bt[ni] = b_t[woff_n + ni * 16 + l15];
        #pragma unroll
        for (int ni = 0; ni < 4; ++ni)
            #pragma unroll
            for (int r = 0; r < 4; ++r) {
                const int ml = woff_m + q * 4 + r;
                const int nl = woff_n + ni * 16 + l15;
                decD[((size_t)(r0 + ml) * BATCH + bb) * ATT + nl] =
                    __builtin_amdgcn_exp2f(CSCALE * (acc[ni][r] + bt[ni]));
            }
    }
    #undef LOADG
    #undef STORES
}

// ---------------------------------------------------------------------------
// Score v7: t-PAIR PACKED fp32. Same 4-term rational per a-quad as v6
// (validated absmax 7.8e-3, bit-identical op order), but the 4 t-values are
// processed as two f32x2 pairs so adds/muls/fmas lower to full-rate VOP3P
// v_pk_* (2 f32/lane/instr): ~56 scalar VALU/g -> ~36 issued ops/g.
// D staged in LDS pre-interleaved [pair][g][{d_i(t0),d_i(t1)}] so packed
// operands are plain float4 loads (register-pair halves, no shuffles).
// E and n_i enter pk ops as scalar splats (op_sel broadcast, free).
// ---------------------------------------------------------------------------
__global__ __launch_bounds__(256) void score_kernel(
    const float* __restrict__ encE, const float* __restrict__ decD,
    const float* __restrict__ v_a, float* __restrict__ out)
{
    __shared__ float dT[2 * 32 * 8];   // [pair][g][i*2+half]
    __shared__ float vS[ATT];
    __shared__ float sumvS;

    const int tid = threadIdx.x;
    const int t0  = blockIdx.x * 4;
    const int b   = blockIdx.y;

    // stage D pair-interleaved: thread -> (pair p, quad g, elem i)
    {
        const int p = tid >> 7;            // 0..1
        const int rem = tid & 127;
        const int g = rem >> 2, i = rem & 3;
        const float dlo = decD[((size_t)(t0 + 2 * p + 0) * BATCH + b) * ATT + g * 4 + i];
        const float dhi = decD[((size_t)(t0 + 2 * p + 1) * BATCH + b) * ATT + g * 4 + i];
        float2 u; u.x = dlo; u.y = dhi;
        *(float2*)(dT + (p * 32 + g) * 8 + i * 2) = u;
    }
    if (tid < 32) {
        *(float4*)(vS + tid * 4) = *(const float4*)(v_a + tid * 4);
    }
    __syncthreads();
    if (tid < 64) {
        float x = vS[tid] + vS[tid + 64];
        #pragma unroll
        for (int o = 32; o > 0; o >>= 1) x += __shfl_down(x, o);
        if (tid == 0) sumvS = x;
    }
    __syncthreads();

    f32x2 accP0 = {0.f, 0.f}, accP1 = {0.f, 0.f};
    const float* __restrict__ ep = encE + ((size_t)b * 32 * SRC_LEN + tid) * 4;

    #pragma unroll
    for (int g = 0; g < 32; ++g) {
        const float4 E  = *(const float4*)(ep + (size_t)g * SRC_LEN * 4);
        const float4 vv = *(const float4*)(vS + g * 4);
        const float n0 = vv.x * E.x, n1 = vv.y * E.y;
        const float n2 = vv.z * E.z, n3 = vv.w * E.w;

        #define PSTEP(ACC, PB)                                                \
        {                                                                     \
            const float4 dA = *(const float4*)(PB);                           \
            const float4 dB = *(const float4*)((PB) + 4);                     \
            const f32x2 x0 = f32x2{dA.x, dA.y} + E.x;                         \
            const f32x2 x1 = f32x2{dA.z, dA.w} + E.y;                         \
            const f32x2 x2 = f32x2{dB.x, dB.y} + E.z;                         \
            const f32x2 x3 = f32x2{dB.z, dB.w} + E.w;                         \
            const f32x2 a01 = x0 * x1, a23 = x2 * x3;                         \
            const f32x2 den = a01 * a23;                                      \
            const f32x2 m01 = __builtin_elementwise_fma(x1, f32x2{n0, n0},    \
                                                        x0 * n1);             \
            const f32x2 m23 = __builtin_elementwise_fma(x3, f32x2{n2, n2},    \
                                                        x2 * n3);             \
            const f32x2 num = __builtin_elementwise_fma(m01, a23, m23 * a01); \
            f32x2 r;                                                          \
            r.x = __builtin_amdgcn_rcpf(den.x);                               \
            r.y = __builtin_amdgcn_rcpf(den.y);                               \
            ACC = __builtin_elementwise_fma(num, r, ACC);                     \
        }
        PSTEP(accP0, dT + g * 8)
        PSTEP(accP1, dT + (32 + g) * 8)
        #undef PSTEP
    }

    const float sv = sumvS;
    out[((size_t)(t0 + 0) * BATCH + b) * SRC_LEN + tid] = sv - 2.0f * accP0.x;
    out[((size_t)(t0 + 1) * BATCH + b) * SRC_LEN + tid] = sv - 2.0f * accP0.y;
    out[((size_t)(t0 + 2) * BATCH + b) * SRC_LEN + tid] = sv - 2.0f * accP1.x;
    out[((size_t)(t0 + 3) * BATCH + b) * SRC_LEN + tid] = sv - 2.0f * accP1.y;
}

extern "C" void kernel_launch(void* const* d_in, const int* in_sizes, int n_in,
                              void* d_out, int out_size, void* d_ws, size_t ws_size,
                              hipStream_t stream) {
    const float* dec_out  = (const float*)d_in[0];
    const float* enc_outs = (const float*)d_in[1];
    const float* W_s      = (const float*)d_in[2];
    const float* W_t      = (const float*)d_in[3];
    const float* b_t      = (const float*)d_in[4];
    const float* v_a      = (const float*)d_in[5];
    float* out = (float*)d_out;

    float* encE = (float*)d_ws;                              // B*32*S*4 = 4 MB : exp(-2*enc_att), [b][a>>2][s][4]
    float* decD = encE + (size_t)BATCH * ATT * SRC_LEN;      // T*B*A    = 4 MB : exp(+2*dec_att), [t][b][a]

    proj_mfma<<<256, 512, 0, stream>>>(dec_out, enc_outs, W_s, W_t, b_t, encE, decD);

    dim3 g3(TRG_LEN / 4, BATCH);
    score_kernel<<<g3, 256, 0, stream>>>(encE, decD, v_a, out);
}